// Round 1
// baseline (26.902 us; speedup 1.0000x reference)
//
#include <hip/hip_runtime.h>

// Problem geometry (fixed by the reference's setup_inputs):
//   im_data  : (1,3,1024,1024) f32  -- unused except Himg=1024
//   feature  : (1,512,256,256) f32  -- unused except H=W=256
//   gt_boxes : (1,128,5) f32  [x1,y1,x2,y2,label]
//   num_boxes: scalar int (1-elem array)
// scale = H/Himg = 256/1024 = 0.25 exactly.
// Output flat layout (float32): mask_pre[65536], norms_pre[1],
//                               mask_cur[65536], norms_cur[1]  -> 131074 elems.
// Semantics: x_union[w] = OR over valid boxes of (w in [x1,x2)),
//            y_union[h] likewise; mask = outer product; norms = 2*sum(mask)
//            (or 1.0 if sum==0 or n<=0).

#define NSLICES 32   // blocks per branch; each block writes 8 mask rows

__global__ __launch_bounds__(256) void mask_gen_kernel(
    const float* __restrict__ boxes_pre, const int* __restrict__ n_pre,
    const float* __restrict__ boxes_cur, const int* __restrict__ n_cur,
    float* __restrict__ out, int nboxes, float scale)
{
    const int branch = blockIdx.x / NSLICES;   // 0 = pre, 1 = cur
    const int slice  = blockIdx.x % NSLICES;
    const float* __restrict__ boxes = branch ? boxes_cur : boxes_pre;
    const int n = branch ? *n_cur : *n_pre;
    float* __restrict__ mask_out = out + (size_t)branch * 65537;

    const int t = threadIdx.x;

    __shared__ float sb[128 * 5];
    __shared__ unsigned char xu_s[256];
    __shared__ unsigned char yu_s[256];
    __shared__ int cnt[2];

    // Stage box data (640 floats) into LDS.
    for (int i = t; i < nboxes * 5; i += 256) sb[i] = boxes[i];
    if (t < 2) cnt[t] = 0;
    __syncthreads();

    // Thread t owns column t (x_union) and row t (y_union).
    bool xu = false, yu = false;
    if (n > 0) {
        for (int i = 0; i < nboxes; ++i) {
            const float lab = sb[i * 5 + 4];
            if (lab != 0.0f) {
                const int x1 = (int)truncf(sb[i * 5 + 0] * scale);
                const int y1 = (int)truncf(sb[i * 5 + 1] * scale);
                const int x2 = (int)truncf(sb[i * 5 + 2] * scale);
                const int y2 = (int)truncf(sb[i * 5 + 3] * scale);
                xu = xu || ((t >= x1) && (t < x2));
                yu = yu || ((t >= y1) && (t < y2));
            }
        }
    }
    xu_s[t] = xu ? 1 : 0;
    yu_s[t] = yu ? 1 : 0;

    // Count set bits for norms: 64-lane ballot per wave, one atomic per wave.
    const unsigned long long bx = __ballot(xu);
    const unsigned long long by = __ballot(yu);
    if ((t & 63) == 0) {
        atomicAdd(&cnt[0], __popcll(bx));
        atomicAdd(&cnt[1], __popcll(by));
    }
    __syncthreads();

    if (slice == 0 && t == 0) {
        const float s = 2.0f * (float)cnt[0] * (float)cnt[1];
        mask_out[65536] = (n > 0 && s != 0.0f) ? s : 1.0f;
    }

    // Write 8 rows of the 256x256 mask. Base offset for branch 1 is odd
    // (65537 floats), so float4 stores would be misaligned -- use scalar
    // stores, lane-coalesced within each 32-thread group.
    const int row_local = t >> 5;       // 0..7
    const int lane      = t & 31;
    const int row       = slice * 8 + row_local;
    const unsigned char rv = yu_s[row];
    float* __restrict__ rowp = mask_out + (size_t)row * 256;
    #pragma unroll
    for (int j = 0; j < 8; ++j) {
        const int col = lane + j * 32;
        rowp[col] = (rv & xu_s[col]) ? 1.0f : 0.0f;
    }
}

extern "C" void kernel_launch(void* const* d_in, const int* in_sizes, int n_in,
                              void* d_out, int out_size, void* d_ws, size_t ws_size,
                              hipStream_t stream) {
    // Input order per setup_inputs(): im_data, feature, gt_boxes_pre,
    // num_boxes_pre, gt_boxes_cur, num_boxes_cur.
    const float* boxes_pre = (const float*)d_in[2];
    const int*   n_pre     = (const int*)d_in[3];
    const float* boxes_cur = (const float*)d_in[4];
    const int*   n_cur     = (const int*)d_in[5];
    float* out = (float*)d_out;

    const int nboxes = in_sizes[2] / 5;   // 128
    const float scale = 0.25f;            // H/Himg = 256/1024

    mask_gen_kernel<<<2 * NSLICES, 256, 0, stream>>>(
        boxes_pre, n_pre, boxes_cur, n_cur, out, nboxes, scale);
}

// Round 2
// 9.565 us; speedup vs baseline: 2.8125x; 2.8125x over previous
//
#include <hip/hip_runtime.h>

// Problem geometry (fixed by the reference's setup_inputs):
//   gt_boxes : (1,128,5) f32  [x1,y1,x2,y2,label]; num_boxes: scalar int.
//   feature H=W=256, im 1024 -> scale = 0.25 exactly.
// Output flat f32: mask_pre[65536], norms_pre[1], mask_cur[65536], norms_cur[1].
// Semantics: x_union[w] = OR over valid(label!=0) boxes of (w in [x1s,x2s)),
//            y_union likewise; mask = outer product; norms = 2*sum(mask),
//            (1.0 if sum==0 or n<=0).
//
// This round: replace the per-thread 128-box scan with box-parallel bit-range
// atomicOr into a 256-bit x bitmask + 256-bit y bitmask (16 LDS words total).
// Column word index == unroll index j in the writer, so the store loop reads
// each bitmask word once per thread.

#define NSLICES 32   // blocks per branch; each block writes 8 mask rows

__global__ __launch_bounds__(256) void mask_gen_kernel(
    const float* __restrict__ boxes_pre, const int* __restrict__ n_pre,
    const float* __restrict__ boxes_cur, const int* __restrict__ n_cur,
    float* __restrict__ out, int nboxes, float scale)
{
    const int branch = blockIdx.x / NSLICES;   // 0 = pre, 1 = cur
    const int slice  = blockIdx.x % NSLICES;
    const float* __restrict__ boxes = branch ? boxes_cur : boxes_pre;
    const int n = branch ? *n_cur : *n_pre;
    float* __restrict__ mask_out = out + (size_t)branch * 65537;

    const int t = threadIdx.x;

    // bm[0..7] = x_union bits (256), bm[8..15] = y_union bits (256).
    __shared__ unsigned int bm[16];
    if (t < 16) bm[t] = 0u;
    __syncthreads();

    if (n > 0 && t < nboxes) {
        const float* __restrict__ b = boxes + t * 5;
        const float lab = b[4];
        if (lab != 0.0f) {
            int x1 = (int)truncf(b[0] * scale);
            int y1 = (int)truncf(b[1] * scale);
            int x2 = (int)truncf(b[2] * scale);
            int y2 = (int)truncf(b[3] * scale);
            x1 = min(max(x1, 0), 256); x2 = min(max(x2, 0), 256);
            y1 = min(max(y1, 0), 256); y2 = min(max(y2, 0), 256);
            if (x2 > x1) {
                for (int w = (x1 >> 5); w <= ((x2 - 1) >> 5); ++w) {
                    const int lo = max(x1 - w * 32, 0);
                    const int hi = min(x2 - w * 32, 32);
                    const unsigned hb = (hi == 32) ? 0xFFFFFFFFu : ((1u << hi) - 1u);
                    const unsigned lb = (lo == 0) ? 0u : ((1u << lo) - 1u);
                    atomicOr(&bm[w], hb & ~lb);
                }
            }
            if (y2 > y1) {
                for (int w = (y1 >> 5); w <= ((y2 - 1) >> 5); ++w) {
                    const int lo = max(y1 - w * 32, 0);
                    const int hi = min(y2 - w * 32, 32);
                    const unsigned hb = (hi == 32) ? 0xFFFFFFFFu : ((1u << hi) - 1u);
                    const unsigned lb = (lo == 0) ? 0u : ((1u << lo) - 1u);
                    atomicOr(&bm[8 + w], hb & ~lb);
                }
            }
        }
    }
    __syncthreads();

    if (slice == 0 && t == 0) {
        int cx = 0, cy = 0;
        #pragma unroll
        for (int w = 0; w < 8; ++w) { cx += __popc(bm[w]); cy += __popc(bm[8 + w]); }
        const float s = 2.0f * (float)cx * (float)cy;
        mask_out[65536] = (n > 0 && s != 0.0f) ? s : 1.0f;
    }

    // Write 8 rows of the 256x256 mask. Branch-1 base offset is odd (65537
    // floats) so stores stay scalar (4B) but lane-coalesced.
    const int row  = slice * 8 + (t >> 5);   // 0..255
    const int lane = t & 31;
    const unsigned yb = (bm[8 + (row >> 5)] >> (row & 31)) & 1u;
    float* __restrict__ rowp = mask_out + (size_t)row * 256;
    #pragma unroll
    for (int j = 0; j < 8; ++j) {
        const unsigned xb = (bm[j] >> lane) & 1u;   // col = lane + 32j -> word j
        rowp[lane + j * 32] = (yb & xb) ? 1.0f : 0.0f;
    }
}

extern "C" void kernel_launch(void* const* d_in, const int* in_sizes, int n_in,
                              void* d_out, int out_size, void* d_ws, size_t ws_size,
                              hipStream_t stream) {
    // Input order: im_data, feature, gt_boxes_pre, num_boxes_pre,
    //              gt_boxes_cur, num_boxes_cur.
    const float* boxes_pre = (const float*)d_in[2];
    const int*   n_pre     = (const int*)d_in[3];
    const float* boxes_cur = (const float*)d_in[4];
    const int*   n_cur     = (const int*)d_in[5];
    float* out = (float*)d_out;

    const int nboxes = in_sizes[2] / 5;   // 128
    const float scale = 0.25f;            // H/Himg = 256/1024

    mask_gen_kernel<<<2 * NSLICES, 256, 0, stream>>>(
        boxes_pre, n_pre, boxes_cur, n_cur, out, nboxes, scale);
}